// Round 14
// baseline (219.444 us; speedup 1.0000x reference)
//
#include <hip/hip_runtime.h>
#include <stdint.h>

#define NB 32768
#define NPASS 4
#define FULL27 0x07FFFFFFu
#define PUZ_PER_BLK 64            // 64 puzzles/block (16 per wave, 4 lanes each)
#define SOLVE_BLKS (NB / PUZ_PER_BLK)   // 512 blocks x 256 threads = 2048 waves
#define BLK_DW 1458               // 64*729/32 dwords of bits per block (exact)
#define BLK_V4 11664              // 64*729/4 float4s per block (exact)

// Per-band bitboard: digit d, band b (rows 3b..3b+2), bit (r*9+c).
// BOX k mask within band: 0x1C0E07 << 3k ; COL c: 0x40201 << c ; ROW r: 0x1FF << 9r
// Flat float layout: puzzle p, digit d, band b, cell j == p*729 + d*81 + b*27 + j.
// Pool layout: bit j of block pool == float blk*46656 + j.
//
// SESSION LEDGER:
//   r15 (216.5us): 3 lanes/puzzle, ds_bpermute. kernel 107us.
//   r16 (213.5us): quad DPP bands. LDS_CONF 3.0M->192K, VALUBusy 42->55.
//   r17 (241.6 REGR): solve at 512 waves -> half the SIMDs empty.
//   r18/r20 (216.2): split kernels. Solve 71.3-72.6us @ VALUBusy 73-75%.
//   r21 (215.6): fused chunked DPP pack. Pack 31us: 1 outstanding load/wave.
//   r22 (209.7, BEST): +launch_bounds(256,2). kernel 101.6.
//   r23 (207.2): sched_barrier pins -> 142 profiled (defeats scheduler).
//   r24 (213.4): global_load_lds ring -> no gain.
//   r25/r26 (223.5 REGR): manual or/shift muls (x*0x40201 was already
//     v_mul_u32_u24) + single-wave stagger (no effect).
//   r27 (221.0): fixpoint early-exit never fires on random data.
//   r28 (213.4): split, full-occupancy coalesced pack: solve 73.0 reproduced,
//     but pack+GAP = 32us — inter-kernel gap eats the occupancy win. Fused
//     r22 remains best. CROSS-ROUND FACT: every fused pack was unroll-1
//     (flat) or hand-chunked (collapsed); compiler-unroll NEVER TESTED.
//   r29 (this): r22 exactly + flat pack loop with #pragma unroll 4 — the
//     4 iterations' uint4 loads are independent & non-aliasing -> compiler
//     hoists 4 loads, counted vmcnt(3..0), 4KB/wave in flight (vs 1KB).
//     VGPR +16 only. Predict VGPR ~64-72, kernel ~88, bench ~196.
//     If VGPR stays 48 / time flat -> pack 31us is a HW floor -> roofline.

__device__ __forceinline__ uint32_t colfold(uint32_t w) {
    return (w | (w >> 9) | (w >> 18)) & 0x1FFu;
}
__device__ __forceinline__ uint32_t colmaj2(uint32_t w) {   // columns with >=2 bits in band
    return ((w & (w >> 9)) | ((w | (w >> 9)) & (w >> 18))) & 0x1FFu;
}
// quad_perm rotations within the 4-lane quad: band b reads band (b+1)%3 / (b-1)%3.
// ctrl = sel0 | sel1<<2 | sel2<<4 | sel3<<6 : [1,2,0,0]=0x09 ; [2,0,1,0]=0x12
__device__ __forceinline__ uint32_t rotA(uint32_t v) {      // from band+1 (mod 3)
    return (uint32_t)__builtin_amdgcn_update_dpp(0, (int)v, 0x09, 0xF, 0xF, true);
}
__device__ __forceinline__ uint32_t rotB(uint32_t v) {      // from band-1 (mod 3)
    return (uint32_t)__builtin_amdgcn_update_dpp(0, (int)v, 0x12, 0xF, 0xF, true);
}
// pack-tree swaps: quad_perm [1,0,3,2]=0xB1 (lane^1), [2,3,0,1]=0x4E (lane^2)
__device__ __forceinline__ uint32_t dppx1(uint32_t v) {
    return (uint32_t)__builtin_amdgcn_update_dpp(0, (int)v, 0xB1, 0xF, 0xF, true);
}
__device__ __forceinline__ uint32_t dppx2(uint32_t v) {
    return (uint32_t)__builtin_amdgcn_update_dpp(0, (int)v, 0x4E, 0xF, 0xF, true);
}

__global__ __launch_bounds__(256, 2)
void sudoku_kernel(const uint32_t* __restrict__ in, float* __restrict__ out,
                   float* __restrict__ solved) {
    __shared__ uint32_t pool[BLK_DW + 2];   // 46656 bits (+pad for extract's 64b read)
    const int tid = threadIdx.x;
    const int q = tid >> 2;                 // puzzle slot 0..63
    const int band = tid & 3;               // 0..2 live, 3 idle in solve
    const int P0 = blockIdx.x * PUZ_PER_BLK;

    // ---------------- PACK (fused, coalesced DPP tree, compiler-unrolled) ------
    // iter i: thread loads float4 #(i*256+tid) (contiguous). Nibble from exp
    // bit 23; DPP xor1 -> byte (even lanes); xor2 -> u16 (lane%4==0); u16 store.
    // unroll 4: independent non-aliasing loads get hoisted -> 4 outstanding
    // dwordx4/wave (4KB in flight vs 1KB at unroll 1 — the r21-r24 latency wall).
    {
        const uint4* src4 = (const uint4*)in + (size_t)blockIdx.x * BLK_V4;
        uint16_t* hp = (uint16_t*)pool;
        #pragma unroll 4
        for (int i = 0; i < 46; ++i) {              // 46*256 = 11776 >= 11664
            int g = i * 256 + tid;
            int gc = g > BLK_V4 - 1 ? BLK_V4 - 1 : g;
            uint4 v = src4[gc];
            // inputs are exactly 0.0f/1.0f -> bit 23 of the pattern is the flag
            uint32_t n = ((v.x >> 23) & 1u) | ((v.y >> 22) & 2u)
                       | ((v.z >> 21) & 4u) | ((v.w >> 20) & 8u);
            uint32_t b = n | (dppx1(n) << 4);       // byte, valid on even lanes
            uint32_t h = b | (dppx2(b) << 8);       // u16, valid on lane%4==0
            if ((tid & 3) == 0) {
                int t = g >> 2;                     // unclamped
                if (t < 2 * BLK_DW) hp[t] = (uint16_t)h;
            }
        }
    }
    __syncthreads();

    // ---- extract 9 band-words for this lane (band 3 reads in-bounds garbage)
    uint32_t bd[9];
    {
        const int bb0 = q * 729 + band * 27;
        #pragma unroll
        for (int d = 0; d < 9; ++d) {
            int bit = bb0 + d * 81;
            int di = bit >> 5, sh = bit & 31;
            uint64_t both = (uint64_t)pool[di] | ((uint64_t)pool[di + 1] << 32);
            bd[d] = (uint32_t)(both >> sh) & FULL27;
        }
    }
    __syncthreads();    // extraction done before pool reuse for expand

    // ---------------- SOLVE (r16/r20-validated quad-DPP logic, unchanged) ------
    #pragma unroll 1
    for (int pass = 0; pass < NPASS; ++pass) {
        // ---------- filter 'box' (band-local) ----------
        {
            uint32_t on = 0, tw = 0, fo = 0;
            #pragma unroll
            for (int d = 0; d < 9; ++d) {
                uint32_t c = on & bd[d];
                on ^= bd[d]; fo |= tw & c; tw ^= c;
            }
            uint32_t ex1 = on & ~tw & ~fo;
            #pragma unroll
            for (int d = 0; d < 9; ++d) {
                uint32_t s = bd[d] & ex1;
                #pragma unroll
                for (int k = 0; k < 3; ++k) {
                    uint32_t bm = 0x1C0E07u << (3 * k);
                    uint32_t sm = s & bm;
                    uint32_t multi = sm & (sm - 1u);
                    uint32_t keep = (sm == 0u) ? 0xFFFFFFFFu : (~bm | (multi ? 0u : sm));
                    bd[d] &= keep;
                }
            }
        }

        // ---------- pointing 'h' (band-local) ----------
        #pragma unroll
        for (int d = 0; d < 9; ++d) {
            uint32_t w = bd[d];
            uint32_t t = (w | (w >> 1) | (w >> 2)) & 0x01249249u;
            uint32_t sum = (t & 0x1FFu) + ((t >> 9) & 0x1FFu) + ((t >> 18) & 0x1FFu);
            uint32_t single = sum & ~(sum >> 1) & 0x49u;
            uint32_t point = t & (single * 0x40201u);
            uint32_t clearm = 0;
            #pragma unroll
            for (int r = 0; r < 3; ++r) {
                uint32_t pr = (point >> (9 * r)) & 0x1FFu;
                uint32_t multi = pr & (pr - 1u);
                uint32_t segkeep = multi ? 0u : pr * 7u;
                uint32_t rc = pr ? ((0x1FFu & ~segkeep) << (9 * r)) : 0u;
                clearm |= rc;
            }
            bd[d] = w & ~clearm;
        }

        // ---------- pointing 'v' (cross-band via DPP) ----------
        {
            uint32_t pnt[9];
            #pragma unroll
            for (int d = 0; d < 9; ++d) {
                uint32_t w = bd[d];
                uint32_t qq = colfold(w);
                uint32_t u = (qq & 0x49u) + ((qq >> 1) & 0x49u) + ((qq >> 2) & 0x49u);
                uint32_t single = u & ~(u >> 1) & 0x49u;
                pnt[d] = qq & (single * 7u);
            }
            #pragma unroll
            for (int d = 0; d < 9; ++d) {
                uint32_t o = rotA(pnt[d]) | rotB(pnt[d]);
                bd[d] &= ~(o * 0x40201u);
            }
        }

        // ---------- unique 'h' (band-local) ----------
        {
            uint32_t hid[9], has = 0;
            #pragma unroll
            for (int d = 0; d < 9; ++d) {
                uint32_t w = bd[d], h = 0;
                #pragma unroll
                for (int r = 0; r < 3; ++r) {
                    uint32_t x = w & (0x1FFu << (9 * r));
                    h |= (x & (x - 1u)) ? 0u : x;
                }
                hid[d] = h; has |= h;
            }
            #pragma unroll
            for (int d = 0; d < 9; ++d) bd[d] = (bd[d] & ~has) | hid[d];
        }

        // ---------- unique 'v' (cross-band via DPP) ----------
        {
            uint32_t hid[9], has = 0;
            #pragma unroll
            for (int d = 0; d < 9; ++d) {
                uint32_t w = bd[d];
                uint32_t q0 = colfold(w), m0 = colmaj2(w);
                uint32_t ex = q0 | (m0 << 9);
                uint32_t ea = rotA(ex);
                uint32_t eb = rotB(ex);
                uint32_t qa = ea & 0x1FFu, ma = ea >> 9;
                uint32_t qb = eb & 0x1FFu, mb = eb >> 9;
                uint32_t ge2 = m0 | ma | mb | (q0 & qa) | (q0 & qb) | (qa & qb);
                uint32_t ex1c = (q0 | qa | qb) & ~ge2;   // column total count == 1
                hid[d] = w & ((ex1c & q0) * 0x40201u);
                has |= hid[d];
            }
            #pragma unroll
            for (int d = 0; d < 9; ++d) bd[d] = (bd[d] & ~has) | hid[d];
        }

        // ---------- unique 'box' (band-local) ----------
        {
            uint32_t hid[9], has = 0;
            #pragma unroll
            for (int d = 0; d < 9; ++d) {
                uint32_t w = bd[d], h = 0;
                #pragma unroll
                for (int k = 0; k < 3; ++k) {
                    uint32_t x = w & (0x1C0E07u << (3 * k));
                    h |= (x & (x - 1u)) ? 0u : x;
                }
                hid[d] = h; has |= h;
            }
            #pragma unroll
            for (int d = 0; d < 9; ++d) bd[d] = (bd[d] & ~has) | hid[d];
        }

        // ---------- doubles 'v' twice (cross-band via DPP) ----------
        #pragma unroll 1
        for (int rep = 0; rep < 2; ++rep) {
            uint32_t on = 0, tw = 0, fo = 0;
            #pragma unroll
            for (int d = 0; d < 9; ++d) {
                uint32_t c = on & bd[d];
                on ^= bd[d]; fo |= tw & c; tw ^= c;
            }
            uint32_t ex2 = tw & ~on & ~fo;
            uint32_t Q[9], K[9];
            #pragma unroll
            for (int d = 0; d < 9; ++d) { Q[d] = bd[d] & ex2; K[d] = 0u; }
            #pragma unroll
            for (int d1 = 0; d1 < 9; ++d1)
                #pragma unroll
                for (int d2 = d1 + 1; d2 < 9; ++d2) {
                    uint32_t P = Q[d1] & Q[d2];
                    uint32_t f0 = colfold(P), g0 = colmaj2(P);
                    uint32_t ex = f0 | (g0 << 9);
                    uint32_t ea = rotA(ex);
                    uint32_t eb = rotB(ex);
                    uint32_t fa = ea & 0x1FFu, ga = ea >> 9;
                    uint32_t fb = eb & 0x1FFu, gb = eb >> 9;
                    // columns with >=2 exact-pair cells across the full column
                    uint32_t dup = g0 | ga | gb | (f0 & fa) | (f0 & fb) | (fa & fb);
                    uint32_t sK = P & (dup * 0x40201u);
                    K[d1] |= sK; K[d2] |= sK;
                }
            #pragma unroll
            for (int d = 0; d < 9; ++d) {
                uint32_t kc = colfold(K[d]);
                uint32_t cols = kc | rotA(kc) | rotB(kc);
                uint32_t em = cols * 0x40201u;
                bd[d] = (bd[d] & ~em) | K[d];
            }
        }

        // ---------- doubles 'box' (band-local) ----------
        {
            uint32_t on = 0, tw = 0, fo = 0;
            #pragma unroll
            for (int d = 0; d < 9; ++d) {
                uint32_t c = on & bd[d];
                on ^= bd[d]; fo |= tw & c; tw ^= c;
            }
            uint32_t ex2 = tw & ~on & ~fo;
            uint32_t Q[9], K[9];
            #pragma unroll
            for (int d = 0; d < 9; ++d) { Q[d] = bd[d] & ex2; K[d] = 0u; }
            #pragma unroll
            for (int d1 = 0; d1 < 9; ++d1)
                #pragma unroll
                for (int d2 = d1 + 1; d2 < 9; ++d2) {
                    uint32_t P = Q[d1] & Q[d2];
                    #pragma unroll
                    for (int k = 0; k < 3; ++k) {
                        uint32_t m = P & (0x1C0E07u << (3 * k));
                        uint32_t s = (m & (m - 1u)) ? m : 0u;
                        K[d1] |= s; K[d2] |= s;
                    }
                }
            #pragma unroll
            for (int d = 0; d < 9; ++d)
                #pragma unroll
                for (int k = 0; k < 3; ++k) {
                    uint32_t bm = 0x1C0E07u << (3 * k);
                    uint32_t t = K[d] & bm;
                    uint32_t mask = t ? (~bm | t) : 0xFFFFFFFFu;
                    bd[d] &= mask;
                }
        }
    } // passes

    // ---------------- solved flag (AND across quad via DPP) ----------------
    {
        uint32_t on = 0, tw = 0, fo = 0;
        #pragma unroll
        for (int d = 0; d < 9; ++d) {
            uint32_t c = on & bd[d];
            on ^= bd[d]; fo |= tw & c; tw ^= c;
        }
        uint32_t okb = ((on & ~tw & ~fo) == FULL27) ? 1u : 0u;
        uint32_t all = okb & rotA(okb) & rotB(okb);
        if (band == 0) solved[P0 + q] = all ? 1.0f : 0.0f;
    }

    // ---------------- EXPAND: repack to pool bitstream -> float4 stores --------
    for (int j = tid; j < BLK_DW + 2; j += 256) pool[j] = 0u;
    __syncthreads();
    if (band != 3) {
        const int pbit = q * 729;
        #pragma unroll
        for (int d = 0; d < 9; ++d) {
            int bitbase = pbit + d * 81 + band * 27;
            int di = bitbase >> 5;
            int sh = bitbase & 31;
            uint64_t both = (uint64_t)bd[d] << sh;
            atomicOr(&pool[di], (uint32_t)both);
            atomicOr(&pool[di + 1], (uint32_t)(both >> 32));
        }
    }
    __syncthreads();
    {
        float4* dst4 = (float4*)(out + (size_t)P0 * 729);  // 46656*blk floats: aligned
        #pragma unroll 4
        for (int i = 0; i < 46; ++i) {                     // 11664 float4s / 256 lanes
            int j = i * 256 + tid;
            if (j < 11664) {
                uint32_t nib = (pool[j >> 3] >> ((j & 7) * 4)) & 0xFu;
                dst4[j] = make_float4((float)(nib & 1u), (float)((nib >> 1) & 1u),
                                      (float)((nib >> 2) & 1u), (float)((nib >> 3) & 1u));
            }
        }
    }
}

extern "C" void kernel_launch(void* const* d_in, const int* in_sizes, int n_in,
                              void* d_out, int out_size, void* d_ws, size_t ws_size,
                              hipStream_t stream) {
    const uint32_t* in = (const uint32_t*)d_in[0];   // float32 bits; 0.0f / 1.0f
    float* out = (float*)d_out;
    float* solved = out + (size_t)NB * 729;
    // single kernel: 512 blocks x 256 threads (2 blocks/CU, 8 waves/CU)
    sudoku_kernel<<<SOLVE_BLKS, 256, 0, stream>>>(in, out, solved);
}